// Round 2
// baseline (37.473 us; speedup 1.0000x reference)
//
#include <hip/hip_runtime.h>

#define NB   4096   // tokens
#define NE   32     // experts
#define DIN  256
#define DOUT 256
#define TM   32     // tokens per tile
#define TN   64     // outputs per tile (DOUT/4)

// ws layout (int units):
//   [0]              ntiles
//   [8 .. 8+2*160)   tile descriptors (expert, token_start) pairs
//   [1024 .. 1057)   offsets[33] (exclusive scan of counts)
//   [2048 .. 6144)   sorted token ids
#define WS_DESC   8
#define WS_OFFS   1024
#define WS_SORT   2048

__global__ __launch_bounds__(1024) void sort_kernel(const int* __restrict__ idx,
                                                    int* __restrict__ ws) {
    __shared__ int cnt[NE];
    __shared__ int pos[NE];
    __shared__ int offs[NE + 1];
    __shared__ int toffs[NE];   // tile-descriptor base per expert
    const int tid = threadIdx.x;
    if (tid < NE) { cnt[tid] = 0; pos[tid] = 0; }
    __syncthreads();

    // 4096 tokens / 1024 threads = 4 each, int4 coalesced
    const int i0 = tid * 4;
    const int4 v = *reinterpret_cast<const int4*>(idx + i0);
    atomicAdd(&cnt[v.x], 1);
    atomicAdd(&cnt[v.y], 1);
    atomicAdd(&cnt[v.z], 1);
    atomicAdd(&cnt[v.w], 1);
    __syncthreads();

    if (tid == 0) {
        int run = 0, trun = 0;
        for (int e = 0; e < NE; ++e) {
            offs[e]  = run;
            toffs[e] = trun;
            run  += cnt[e];
            trun += (cnt[e] + TM - 1) / TM;
        }
        offs[NE] = run;
        ws[0] = trun;
    }
    __syncthreads();

    // parallel descriptor build: thread e writes its expert's tiles
    if (tid < NE) {
        const int c = cnt[tid];
        const int base = offs[tid];
        int nt = toffs[tid];
        for (int t = 0; t < c; t += TM) {
            ws[WS_DESC + 2 * nt]     = tid;
            ws[WS_DESC + 2 * nt + 1] = base + t;
            ++nt;
        }
    }
    if (tid <= NE) ws[WS_OFFS + tid] = offs[tid];

    int* sorted = ws + WS_SORT;
    int r;
    r = atomicAdd(&pos[v.x], 1); sorted[offs[v.x] + r] = i0 + 0;
    r = atomicAdd(&pos[v.y], 1); sorted[offs[v.y] + r] = i0 + 1;
    r = atomicAdd(&pos[v.z], 1); sorted[offs[v.z] + r] = i0 + 2;
    r = atomicAdd(&pos[v.w], 1); sorted[offs[v.w] + r] = i0 + 3;
}

__global__ __launch_bounds__(256) void gemm_kernel(const float* __restrict__ x,
                                                   const float* __restrict__ w,
                                                   const float* __restrict__ bias,
                                                   const int* __restrict__ ws,
                                                   float* __restrict__ out) {
    const int ntiles = ws[0];
    const int tile = blockIdx.x;
    if (tile >= ntiles) return;

    const int e     = ws[WS_DESC + 2 * tile];
    const int start = ws[WS_DESC + 2 * tile + 1];
    const int ende  = ws[WS_OFFS + e + 1];
    const int m     = min(TM, ende - start);
    const int* __restrict__ sorted = ws + WS_SORT;
    const int obase = blockIdx.y * TN;

    __shared__ float xs[DIN][TM];   // 32 KB, [k][token]

    const int tid = threadIdx.x;

    // ---- stage x tile (transposed) into LDS ----
    {
        const int t = tid & 31;        // token slot
        const int g = tid >> 5;        // 0..7 k-groups
        const int trow = sorted[start + min(t, m - 1)];
        const float* xrow = x + (size_t)trow * DIN;
#pragma unroll
        for (int j = 0; j < 8; ++j) {
            const int k0 = (g * 8 + j) * 4;
            const float4 vv = *reinterpret_cast<const float4*>(xrow + k0);
            xs[k0 + 0][t] = vv.x;
            xs[k0 + 1][t] = vv.y;
            xs[k0 + 2][t] = vv.z;
            xs[k0 + 3][t] = vv.w;
        }
    }
    __syncthreads();

    // ---- main loop: thread tile 4 tokens x 2 outputs, 8-deep W prefetch ----
    const int og = tid & 31;   // output pair: 32 x 2 = 64 outs
    const int tg = tid >> 5;   // token quad:   8 x 4 = 32 tokens
    const float* wp = w + (size_t)e * DIN * DOUT + obase + og * 2;

    float acc[4][2] = {};   // [token][out]
    for (int k0 = 0; k0 < DIN; k0 += 8) {
        float2 wv[8];
#pragma unroll
        for (int j = 0; j < 8; ++j)
            wv[j] = *reinterpret_cast<const float2*>(wp + (size_t)(k0 + j) * DOUT);
#pragma unroll
        for (int j = 0; j < 8; ++j) {
            const float4 xv = *reinterpret_cast<const float4*>(&xs[k0 + j][tg * 4]);
            acc[0][0] = fmaf(xv.x, wv[j].x, acc[0][0]);
            acc[0][1] = fmaf(xv.x, wv[j].y, acc[0][1]);
            acc[1][0] = fmaf(xv.y, wv[j].x, acc[1][0]);
            acc[1][1] = fmaf(xv.y, wv[j].y, acc[1][1]);
            acc[2][0] = fmaf(xv.z, wv[j].x, acc[2][0]);
            acc[2][1] = fmaf(xv.z, wv[j].y, acc[2][1]);
            acc[3][0] = fmaf(xv.w, wv[j].x, acc[3][0]);
            acc[3][1] = fmaf(xv.w, wv[j].y, acc[3][1]);
        }
    }

    // ---- epilogue: add bias, scatter to out rows ----
    const float2 bv = *reinterpret_cast<const float2*>(bias + (size_t)e * DOUT + obase + og * 2);
#pragma unroll
    for (int tt = 0; tt < 4; ++tt) {
        const int tl = tg * 4 + tt;
        if (tl < m) {
            const int row = sorted[start + tl];
            float2 o;
            o.x = acc[tt][0] + bv.x;
            o.y = acc[tt][1] + bv.y;
            *reinterpret_cast<float2*>(out + (size_t)row * DOUT + obase + og * 2) = o;
        }
    }
}

extern "C" void kernel_launch(void* const* d_in, const int* in_sizes, int n_in,
                              void* d_out, int out_size, void* d_ws, size_t ws_size,
                              hipStream_t stream) {
    const float* x      = (const float*)d_in[0];
    const int*   index  = (const int*)d_in[1];
    const float* weight = (const float*)d_in[2];
    const float* bias   = (const float*)d_in[3];
    float* out = (float*)d_out;
    int* ws = (int*)d_ws;

    sort_kernel<<<1, 1024, 0, stream>>>(index, ws);

    // worst-case tiles: 128 full + up to 31 partial = 159
    dim3 grid(160, 4);
    gemm_kernel<<<grid, 256, 0, stream>>>(x, weight, bias, ws, out);
}

// Round 3
// 35.587 us; speedup vs baseline: 1.0530x; 1.0530x over previous
//
#include <hip/hip_runtime.h>

#define NE   32
#define DIN  256
#define DOUT 256
#define TM   32     // tokens per tile
#define TN   64     // outputs per tile

// Fully fused: every block recomputes routing from the index array (16 KB),
// deterministically identical across blocks, then runs its 32x64 GEMM tile.
__global__ __launch_bounds__(256) void moe_fused_kernel(
    const float* __restrict__ x, const int* __restrict__ idx,
    const float* __restrict__ w, const float* __restrict__ bias,
    float* __restrict__ out)
{
    __shared__ int   cnt[NE];
    __shared__ int   wcnt[4];
    __shared__ int   sel[TM];
    __shared__ float xs[DIN][TM];   // 32 KB, [k][token]

    const int tid   = threadIdx.x;
    const int T     = blockIdx.x;       // global tile id
    const int obase = blockIdx.y * TN;

    // ---- A: load all 4096 indices, 4 int4 per thread (coalesced) ----
    const int4 c0 = *reinterpret_cast<const int4*>(idx + 0 * 1024 + tid * 4);
    const int4 c1 = *reinterpret_cast<const int4*>(idx + 1 * 1024 + tid * 4);
    const int4 c2 = *reinterpret_cast<const int4*>(idx + 2 * 1024 + tid * 4);
    const int4 c3 = *reinterpret_cast<const int4*>(idx + 3 * 1024 + tid * 4);

    // ---- B: histogram ----
    if (tid < NE) cnt[tid] = 0;
    __syncthreads();
    atomicAdd(&cnt[c0.x], 1); atomicAdd(&cnt[c0.y], 1); atomicAdd(&cnt[c0.z], 1); atomicAdd(&cnt[c0.w], 1);
    atomicAdd(&cnt[c1.x], 1); atomicAdd(&cnt[c1.y], 1); atomicAdd(&cnt[c1.z], 1); atomicAdd(&cnt[c1.w], 1);
    atomicAdd(&cnt[c2.x], 1); atomicAdd(&cnt[c2.y], 1); atomicAdd(&cnt[c2.z], 1); atomicAdd(&cnt[c2.w], 1);
    atomicAdd(&cnt[c3.x], 1); atomicAdd(&cnt[c3.y], 1); atomicAdd(&cnt[c3.z], 1); atomicAdd(&cnt[c3.w], 1);
    __syncthreads();

    // ---- C: tile -> (expert, selection window) ; replicated scan, broadcast LDS reads ----
    int e = -1, sel_lo = 0, m = 0;
    {
        int tp = 0;
        for (int ee = 0; ee < NE; ++ee) {
            const int ce = cnt[ee];
            const int nt = (ce + TM - 1) >> 5;
            if (e < 0 && T < tp + nt) { e = ee; sel_lo = (T - tp) * TM; m = min(TM, ce - sel_lo); }
            tp += nt;
        }
    }
    if (e < 0) return;   // block-uniform: whole block exits, no barrier hazard

    // ---- D: ballot-based stable selection of this tile's tokens ----
    const int lane = tid & 63;
    const int wid  = tid >> 6;
    const unsigned long long lt = (1ull << lane) - 1ull;
    int running = 0;

#define SEL_ROUND(cr, R)                                                                             \
    {                                                                                                \
        const unsigned long long m0 = __ballot((cr).x == e);                                         \
        const unsigned long long m1 = __ballot((cr).y == e);                                         \
        const unsigned long long m2 = __ballot((cr).z == e);                                         \
        const unsigned long long m3 = __ballot((cr).w == e);                                         \
        const int p0 = __popcll(m0), p1 = __popcll(m1), p2 = __popcll(m2), p3 = __popcll(m3);        \
        if (lane == 0) wcnt[wid] = p0 + p1 + p2 + p3;                                                \
        __syncthreads();                                                                             \
        int wb = running;                                                                            \
        if (wid > 0) wb += wcnt[0];                                                                  \
        if (wid > 1) wb += wcnt[1];                                                                  \
        if (wid > 2) wb += wcnt[2];                                                                  \
        const int b0 = wb, b1 = b0 + p0, b2 = b1 + p1, b3 = b2 + p2;                                 \
        const int tokbase = (R) * 1024 + tid * 4;                                                    \
        if ((cr).x == e) { const int o = b0 + __popcll(m0 & lt) - sel_lo; if ((unsigned)o < (unsigned)TM) sel[o] = tokbase + 0; } \
        if ((cr).y == e) { const int o = b1 + __popcll(m1 & lt) - sel_lo; if ((unsigned)o < (unsigned)TM) sel[o] = tokbase + 1; } \
        if ((cr).z == e) { const int o = b2 + __popcll(m2 & lt) - sel_lo; if ((unsigned)o < (unsigned)TM) sel[o] = tokbase + 2; } \
        if ((cr).w == e) { const int o = b3 + __popcll(m3 & lt) - sel_lo; if ((unsigned)o < (unsigned)TM) sel[o] = tokbase + 3; } \
        running += wcnt[0] + wcnt[1] + wcnt[2] + wcnt[3];                                            \
        __syncthreads();                                                                             \
    }

    SEL_ROUND(c0, 0)
    if (running < sel_lo + m) SEL_ROUND(c1, 1)   // block-uniform early exit
    if (running < sel_lo + m) SEL_ROUND(c2, 2)
    if (running < sel_lo + m) SEL_ROUND(c3, 3)
#undef SEL_ROUND

    // ---- E: stage x tile (transposed) into LDS ----
    {
        const int t = tid & 31;        // token slot
        const int g = tid >> 5;        // k-group
        const int trow = sel[min(t, m - 1)];
        const float* xrow = x + (size_t)trow * DIN;
#pragma unroll
        for (int j = 0; j < 8; ++j) {
            const int k0 = (g * 8 + j) * 4;
            const float4 vv = *reinterpret_cast<const float4*>(xrow + k0);
            xs[k0 + 0][t] = vv.x;
            xs[k0 + 1][t] = vv.y;
            xs[k0 + 2][t] = vv.z;
            xs[k0 + 3][t] = vv.w;
        }
    }
    __syncthreads();

    // ---- F: main loop, thread tile 4 tokens x 2 outputs, 8-deep W prefetch ----
    const int og = tid & 31;   // 32 x 2 = 64 outputs
    const int tg = tid >> 5;   //  8 x 4 = 32 tokens
    const float* wp = w + (size_t)e * DIN * DOUT + obase + og * 2;

    float acc[4][2] = {};
    for (int k0 = 0; k0 < DIN; k0 += 8) {
        float2 wv[8];
#pragma unroll
        for (int j = 0; j < 8; ++j)
            wv[j] = *reinterpret_cast<const float2*>(wp + (size_t)(k0 + j) * DOUT);
#pragma unroll
        for (int j = 0; j < 8; ++j) {
            const float4 xv = *reinterpret_cast<const float4*>(&xs[k0 + j][tg * 4]);
            acc[0][0] = fmaf(xv.x, wv[j].x, acc[0][0]);
            acc[0][1] = fmaf(xv.x, wv[j].y, acc[0][1]);
            acc[1][0] = fmaf(xv.y, wv[j].x, acc[1][0]);
            acc[1][1] = fmaf(xv.y, wv[j].y, acc[1][1]);
            acc[2][0] = fmaf(xv.z, wv[j].x, acc[2][0]);
            acc[2][1] = fmaf(xv.z, wv[j].y, acc[2][1]);
            acc[3][0] = fmaf(xv.w, wv[j].x, acc[3][0]);
            acc[3][1] = fmaf(xv.w, wv[j].y, acc[3][1]);
        }
    }

    // ---- G: epilogue ----
    const float2 bv = *reinterpret_cast<const float2*>(bias + (size_t)e * DOUT + obase + og * 2);
#pragma unroll
    for (int tt = 0; tt < 4; ++tt) {
        const int tl = tg * 4 + tt;
        if (tl < m) {
            const int row = sel[tl];
            float2 o;
            o.x = acc[tt][0] + bv.x;
            o.y = acc[tt][1] + bv.y;
            *reinterpret_cast<float2*>(out + (size_t)row * DOUT + obase + og * 2) = o;
        }
    }
}

extern "C" void kernel_launch(void* const* d_in, const int* in_sizes, int n_in,
                              void* d_out, int out_size, void* d_ws, size_t ws_size,
                              hipStream_t stream) {
    const float* x      = (const float*)d_in[0];
    const int*   index  = (const int*)d_in[1];
    const float* weight = (const float*)d_in[2];
    const float* bias   = (const float*)d_in[3];
    float* out = (float*)d_out;

    // worst case tiles: 128 full + 31 partial = 159
    dim3 grid(160, 4);
    moe_fused_kernel<<<grid, 256, 0, stream>>>(x, index, weight, bias, out);
}